// Round 6
// baseline (213.011 us; speedup 1.0000x reference)
//
#include <hip/hip_runtime.h>
#include <stdint.h>

#define OBS_LEN 12
#define KS 20
#define BB 2048
#define HD 128
#define MIDD 256
#define NCQ 2

using f32x4  = __attribute__((ext_vector_type(4))) float;
using bf16x8 = __attribute__((ext_vector_type(8))) short;

static __device__ __forceinline__ short f2bf(float f){
  return __builtin_bit_cast(short, (__bf16)f);   // RNE convert
}
static __device__ __forceinline__ uint32_t pack2(float a, float b){
  return (uint32_t)(uint16_t)f2bf(a) | ((uint32_t)(uint16_t)f2bf(b) << 16);
}
static __device__ __forceinline__ float hsig(float x){
  return fminf(fmaxf(fmaf(x, 0.16666666666666666f, 0.5f), 0.f), 1.f);
}
static __device__ __forceinline__ float clip1(float x){
  return fminf(fmaxf(x, -1.f), 1.f);
}
static __device__ __forceinline__ f32x4 mm(bf16x8 a, bf16x8 b, f32x4 c){
  return __builtin_amdgcn_mfma_f32_16x16x32_bf16(a, b, c, 0, 0, 0);
}
static __device__ __forceinline__ bf16x8 ldh(const uint16_t* buf, int row, int q, int p){
  return *reinterpret_cast<const bf16x8*>(&buf[(row*HD + q*32 + p*8) ^ ((row&7)*8)]);
}
static __device__ __forceinline__ bf16x8 lda(const uint16_t* buf, int row, int q, int p){
  return *reinterpret_cast<const bf16x8*>(&buf[(row*MIDD + q*32 + p*8) ^ ((row&7)*8)]);
}

__global__ __launch_bounds__(512, 2)
void CRMF_35296041239144_kernel(
    const float* __restrict__ obs,  const float* __restrict__ pred,
    const float* __restrict__ mw0,  const float* __restrict__ mb0,
    const float* __restrict__ mw1,  const float* __restrict__ mb1,
    const float* __restrict__ wih,  const float* __restrict__ whh,
    const float* __restrict__ bih,  const float* __restrict__ bhh,
    const float* __restrict__ oww,  const float* __restrict__ obb,
    float* __restrict__ outp)
{
  __shared__ __align__(16) uint16_t hbuf[2][32*HD];  // 16 KB h-state, double buffered
  __shared__ __align__(16) uint16_t abuf[32*MIDD];   // 16 KB MLP activations
  __shared__ __align__(16) uint16_t ofrag[4*64*8];   // 4 KB out_w B-fragments
  __shared__ float2 xbuf[OBS_LEN][32];               // 3 KB shifted obs
  __shared__ float  ostage[OBS_LEN][64];             // 3 KB output staging

  const int tid = threadIdx.x;
  const int w   = tid >> 6;          // wave 0..7
  const int l   = tid & 63;
  const int p   = (tid >> 4) & 3;
  const int ln  = tid & 15;
  const int wofs = w * 16;           // this wave's 16-hd slice
  const bool w7 = (w == 7);

  const int b   = blockIdx.x;        // 512 blocks, 2 per CU
  const int b0  = (b & 63) * 32;
  const int nch = (b < 256) ? 3 : 2; // 256*3 + 256*2 = 1280 chunks

  // ---- shifted obs ----
  if (tid < OBS_LEN*32){
    int t = tid >> 5, cc = tid & 31;
    int st = t ? (t-1) : 0;
    const float* pp = obs + ((size_t)st*BB + b0 + cc)*3;
    xbuf[t][cc] = make_float2(pp[0], pp[1]);
  }
  // ---- out_w fragments -> LDS ----
  if (w == 0){
    #pragma unroll
    for (int q=0; q<4; ++q){
      bf16x8 wf;
      #pragma unroll
      for (int j=0; j<8; ++j){
        int k = q*32 + p*8 + j;
        wf[j] = (ln < NCQ) ? f2bf(oww[k*NCQ + ln]) : (short)0;
      }
      *reinterpret_cast<bf16x8*>(&ofrag[(q*64 + l)*8]) = wf;
    }
  }
  const float obv = (ln < NCQ) ? obb[ln] : 0.f;

  // ---- w_hh -> register fragments: 16 cols x 4 gates per wave (64 VGPR) ----
  bf16x8 wfrag[4][4];
  float wihA[4], wihB[4], biasv[4];
  #pragma unroll
  for (int gate=0; gate<4; ++gate){
    int col = gate*128 + wofs + ln;
    wihA[gate]  = wih[col*2];
    wihB[gate]  = wih[col*2+1];
    biasv[gate] = bih[col] + bhh[col];
    #pragma unroll
    for (int q=0; q<4; ++q){
      const float* s = whh + col*HD + q*32 + p*8;
      float4 f0 = *reinterpret_cast<const float4*>(s);
      float4 f1 = *reinterpret_cast<const float4*>(s+4);
      bf16x8 wf;
      wf[0]=f2bf(f0.x); wf[1]=f2bf(f0.y); wf[2]=f2bf(f0.z); wf[3]=f2bf(f0.w);
      wf[4]=f2bf(f1.x); wf[5]=f2bf(f1.y); wf[6]=f2bf(f1.z); wf[7]=f2bf(f1.w);
      wfrag[gate][q] = wf;
    }
  }

  // ---- chunks: cid = b + 512*i  (same b0 per block; kk = b>>6 + 8i) ----
  #pragma unroll 1
  for (int i=0; i<nch; ++i){
    const int kk = (b >> 6) + 8*i;

    __syncthreads();                 // c=0: ofrag/xbuf ready; else WAR on hbuf/ostage
    // stage h0 -> hbuf[0] (512 threads, 2 float4 each)
    {
      const float* src = pred + ((size_t)(kk*BB + b0))*HD;
      #pragma unroll
      for (int it=0; it<2; ++it){
        int u = tid + it*512;
        int row = u >> 5, c4 = (u & 31)*4;
        float4 v = *reinterpret_cast<const float4*>(src + row*HD + c4);
        int e = (row*HD + c4) ^ ((row&7)*8);
        *reinterpret_cast<uint32_t*>(&hbuf[0][e])   = pack2(v.x, v.y);
        *reinterpret_cast<uint32_t*>(&hbuf[0][e+2]) = pack2(v.z, v.w);
      }
    }
    __syncthreads();

    // ---- MLP GEMM1: [32,128] @ map_w0 -> [32,256]; 32 cols/wave ----
    {
      f32x4 acc1[2][2];
      #pragma unroll
      for (int ct=0; ct<2; ++ct){
        float mb = mb0[w*32 + ct*16 + ln];
        f32x4 v = {mb,mb,mb,mb};
        acc1[0][ct]=v; acc1[1][ct]=v;
      }
      #pragma unroll
      for (int q=0; q<4; ++q){
        bf16x8 af0 = ldh(hbuf[0], ln, q, p), af1 = ldh(hbuf[0], 16+ln, q, p);
        #pragma unroll
        for (int ct=0; ct<2; ++ct){
          bf16x8 wf;
          #pragma unroll
          for (int j=0; j<8; ++j)
            wf[j] = f2bf(mw0[(q*32+p*8+j)*MIDD + (w*32 + ct*16 + ln)]);
          acc1[0][ct] = mm(af0, wf, acc1[0][ct]);
          acc1[1][ct] = mm(af1, wf, acc1[1][ct]);
        }
      }
      #pragma unroll
      for (int rt=0; rt<2; ++rt)
      #pragma unroll
      for (int ct=0; ct<2; ++ct)
      #pragma unroll
      for (int r=0; r<4; ++r){
        float v = acc1[rt][ct][r];
        v = (v>0.f)? v : 0.01f*v;
        int row = rt*16 + p*4 + r;
        abuf[(row*MIDD + w*32 + ct*16 + ln) ^ ((row&7)*8)] = (uint16_t)f2bf(v);
      }
    }
    __syncthreads();                 // abuf ready; hbuf[0] reads done

    // ---- MLP GEMM2: [32,256] @ map_w1 -> h_init -> hbuf[0]; 16 cols/wave ----
    float c_[2][4];
    {
      f32x4 acc2[2];
      float mb = mb1[wofs + ln];
      f32x4 v = {mb,mb,mb,mb};
      acc2[0]=v; acc2[1]=v;
      #pragma unroll
      for (int q=0; q<8; ++q){
        bf16x8 af0 = lda(abuf, ln, q, p), af1 = lda(abuf, 16+ln, q, p);
        bf16x8 wf;
        #pragma unroll
        for (int j=0; j<8; ++j)
          wf[j] = f2bf(mw1[(q*32+p*8+j)*HD + wofs + ln]);
        acc2[0] = mm(af0, wf, acc2[0]);
        acc2[1] = mm(af1, wf, acc2[1]);
      }
      #pragma unroll
      for (int rt=0; rt<2; ++rt)
      #pragma unroll
      for (int r=0; r<4; ++r){
        int row = rt*16 + p*4 + r;
        hbuf[0][(row*HD + wofs + ln) ^ ((row&7)*8)] = (uint16_t)f2bf(acc2[rt][r]);
        c_[rt][r] = 0.f;
      }
    }
    __syncthreads();                 // h_init visible

    // ---- 12 recurrent steps, double-buffered h: ONE barrier per step ----
    #pragma unroll 1
    for (int t=0; t<OBS_LEN; ++t){
      const int cur = t & 1, nxt = cur ^ 1;
      f32x4 acc[2][4];
      #pragma unroll
      for (int rt=0; rt<2; ++rt){
        #pragma unroll
        for (int r=0; r<4; ++r){
          float2 xv = xbuf[t][rt*16 + p*4 + r];
          #pragma unroll
          for (int gate=0; gate<4; ++gate)
            acc[rt][gate][r] = fmaf(xv.x, wihA[gate], fmaf(xv.y, wihB[gate], biasv[gate]));
        }
      }
      f32x4 a8[2];
      if (w7 && t>0){ f32x4 v={obv,obv,obv,obv}; a8[0]=v; a8[1]=v; }
      #pragma unroll
      for (int q=0; q<4; ++q){
        bf16x8 af0 = ldh(hbuf[cur], ln, q, p), af1 = ldh(hbuf[cur], 16+ln, q, p);
        #pragma unroll
        for (int gate=0; gate<4; ++gate){
          acc[0][gate] = mm(af0, wfrag[gate][q], acc[0][gate]);
          acc[1][gate] = mm(af1, wfrag[gate][q], acc[1][gate]);
        }
        if (w7 && t>0){
          bf16x8 of = *reinterpret_cast<const bf16x8*>(&ofrag[(q*64 + l)*8]);
          a8[0] = mm(af0, of, a8[0]);
          a8[1] = mm(af1, of, a8[1]);
        }
      }
      if (w7 && t>0 && ln<NCQ){
        #pragma unroll
        for (int rt=0; rt<2; ++rt)
        #pragma unroll
        for (int r=0; r<4; ++r)
          ostage[t-1][(rt*16 + p*4 + r)*NCQ + ln] = a8[rt][r];
      }
      #pragma unroll
      for (int rt=0; rt<2; ++rt)
      #pragma unroll
      for (int r=0; r<4; ++r){
        float iv = hsig(acc[rt][0][r]);
        float fv = hsig(acc[rt][1][r]);
        float gv = clip1(acc[rt][2][r]);
        float ov = hsig(acc[rt][3][r]);
        float cv = fmaf(fv, c_[rt][r], iv*gv);
        c_[rt][r] = cv;
        int row = rt*16 + p*4 + r;
        hbuf[nxt][(row*HD + wofs + ln) ^ ((row&7)*8)] = (uint16_t)f2bf(ov * clip1(cv));
      }
      __syncthreads();               // h[nxt] visible; (WAR on cur is 2 barriers away)
    }

    // ---- final out_11 = h_12 @ out_w + out_b  (final h is in hbuf[0]) ----
    if (w7){
      f32x4 o0 = {obv,obv,obv,obv}, o1 = o0;
      #pragma unroll
      for (int q=0; q<4; ++q){
        bf16x8 af0 = ldh(hbuf[0], ln, q, p), af1 = ldh(hbuf[0], 16+ln, q, p);
        bf16x8 of = *reinterpret_cast<const bf16x8*>(&ofrag[(q*64 + l)*8]);
        o0 = mm(af0, of, o0);
        o1 = mm(af1, of, o1);
      }
      if (ln < NCQ){
        #pragma unroll
        for (int r=0; r<4; ++r){
          ostage[11][(     p*4 + r)*NCQ + ln] = o0[r];
          ostage[11][(16 + p*4 + r)*NCQ + ln] = o1[r];
        }
      }
    }
    __syncthreads();                 // ostage complete

    // ---- cooperative coalesced output store: 12 x 256B segments ----
    for (int u = tid; u < OBS_LEN*64; u += 512){
      int t = u >> 6, e = u & 63;
      outp[((size_t)(t*KS + kk)*BB + b0)*NCQ + e] = ostage[t][e];
    }
  }
}

extern "C" void kernel_launch(void* const* d_in, const int* in_sizes, int n_in,
                              void* d_out, int out_size, void* d_ws, size_t ws_size,
                              hipStream_t stream) {
  (void)in_sizes; (void)n_in; (void)d_ws; (void)ws_size; (void)out_size;
  CRMF_35296041239144_kernel<<<dim3(512), dim3(512), 0, stream>>>(
      (const float*)d_in[0], (const float*)d_in[1], (const float*)d_in[2],
      (const float*)d_in[3], (const float*)d_in[4], (const float*)d_in[5],
      (const float*)d_in[6], (const float*)d_in[7], (const float*)d_in[8],
      (const float*)d_in[9], (const float*)d_in[10], (const float*)d_in[11],
      (float*)d_out);
}